// Round 13
// baseline (311.636 us; speedup 1.0000x reference)
//
#include <hip/hip_runtime.h>
#include <hip/hip_bf16.h>

#define HW 16384
#define NB 8
#define NC 192
#define NC3 576
#define NHEADS 4
#define CPH 48

typedef __attribute__((ext_vector_type(8))) short short8v;
typedef __attribute__((ext_vector_type(4))) float f32x4;

__device__ __forceinline__ float bf2f(ushort u) {
    union { unsigned int u; float f; } w; w.u = ((unsigned int)u) << 16; return w.f;
}
__device__ __forceinline__ ushort f2bf(float f) {
    union { float f; unsigned int u; } w; w.f = f;
    return (ushort)((w.u + 0x7FFFu + ((w.u >> 16) & 1u)) >> 16);
}
// packed f32x2 -> bf16x2 (RNE), single VALU inst; lo -> [15:0], hi -> [31:16]
__device__ __forceinline__ unsigned int pkbf(float lo, float hi) {
    unsigned int r;
    asm("v_cvt_pk_bf16_f32 %0, %1, %2" : "=v"(r) : "v"(lo), "v"(hi));
    return r;
}

// ---------------- prep: convert w_in (576x192 f32) to bf16 ----------------
__global__ __launch_bounds__(256) void k_prep(const float* __restrict__ w_in,
                                              ushort* __restrict__ w_bf) {
    int i = blockIdx.x * 256 + threadIdx.x;
    if (i < NC3 * NC) w_bf[i] = f2bf(w_in[i]);
}

// ------- GEMM v8: dbuf + issue-after-barrier (barrier drains nothing) -----
// Out[b][m][n] = sum_k A[b][m][k] * B[b][k][n],  K = 192.
// Grid: (n-chunk, m-tile, b) -- mt-blocks sharing a B chunk differ by GX in
// linear id (GX % 8 == 0) -> same XCD -> chunk fetched from HBM once.
// A wave-fragments in VGPRs (loaded once).
// Schedule (1 barrier/step; loads issued AFTER the barrier so the compiler's
// vmcnt(0)-before-s_barrier drains ~nothing; load latency covered by the
// compute phase; store-acks covered by write_stage):
//   write(buf0); barrier; load(1);
//   step s: compute(buf[s&1]); storeC(s); write(buf[~s&1]); barrier; load(s+2)
// Race-free: reads of buffer X (step s-1) complete before barrier s-1; the
// write to X happens only after that barrier.
// LDS addressing (8B granules g = k>>2):
//   addr_ushort(n,k) = n*196 + ((g ^ (((n>>2)&7)<<1)) << 2) + (k&3)
// Staging mapping (256B global segments): nl=(t&15)*4, kq=t>>4.
template<bool B_F32, bool OUT_F32, int STEPS>
__global__ __launch_bounds__(256) void k_gemm8(
    const ushort* __restrict__ Abase, long aStride,
    const void* __restrict__ Bp, long bStride,
    void* __restrict__ Op, long oStride)
{
    __shared__ ushort Bs0[64 * 196];
    __shared__ ushort Bs1[64 * 196];
    const int t = threadIdx.x;
    const int ncnk = blockIdx.x, mt = blockIdx.y, b = blockIdx.z;
    const int wid = t >> 6, lane = t & 63;
    const int wm = (wid >> 1) * 32, wn = (wid & 1) * 32;
    const int lr = lane & 15, lk = lane >> 4;

    // ---- A fragments in registers (rows k-contiguous)
    short8v a[2][6];
    {
        const ushort* A = Abase + (long)b * aStride
                        + (long)(mt * 64 + wm + lr) * NC + lk * 8;
        #pragma unroll
        for (int mi = 0; mi < 2; mi++) {
            #pragma unroll
            for (int ks = 0; ks < 6; ks++)
                a[mi][ks] = *(const short8v*)(A + mi * 16 * NC + ks * 32);
        }
    }

    const int nl = (t & 15) * 4;     // 4 consecutive n this thread stages
    const int kq = t >> 4;           // k-group: k = kq*12 .. kq*12+11
    const int k0 = kq * 12;
    const int wmsk = (t & 7) << 1;   // = ((n>>2)&7)<<1 for n = nl+i (i<4)
    const long nbase = (long)ncnk * (STEPS * 64);

    float4 fr[12];
    ushort4 ur[12];

    auto load_stage = [&](int s) {
        long n0 = nbase + s * 64;
        if constexpr (B_F32) {
            const float* B = (const float*)Bp + (long)b * bStride
                           + (long)k0 * HW + n0 + nl;
            #pragma unroll
            for (int kk = 0; kk < 12; kk++)
                fr[kk] = *(const float4*)(B + (long)kk * HW);
        } else {
            const ushort* B = (const ushort*)Bp + (long)b * bStride
                            + (long)k0 * HW + n0 + nl;
            #pragma unroll
            for (int kk = 0; kk < 12; kk++)
                ur[kk] = *(const ushort4*)(B + (long)kk * HW);
        }
    };

    auto write_stage = [&](ushort* BsBuf) {
        #pragma unroll
        for (int i = 0; i < 4; i++) {     // n = nl + i (compile-time i)
            const int n = nl + i;
            unsigned int u[6];            // k0..k0+11 packed as bf16x2
            if constexpr (B_F32) {
                #pragma unroll
                for (int p = 0; p < 6; p++)
                    u[p] = pkbf(((const float*)&fr[2 * p])[i],
                                ((const float*)&fr[2 * p + 1])[i]);
            } else {
                #pragma unroll
                for (int p = 0; p < 6; p++) {
                    unsigned int lo = ((const ushort*)&ur[2 * p])[i];
                    unsigned int hi = ((const ushort*)&ur[2 * p + 1])[i];
                    u[p] = lo | (hi << 16);
                }
            }
            #pragma unroll
            for (int seg = 0; seg < 3; seg++) {
                const int g = 3 * kq + seg;          // unswizzled 8B granule
                *(uint2*)&BsBuf[n * 196 + ((g ^ wmsk) << 2)] =
                    make_uint2(u[2 * seg], u[2 * seg + 1]);
            }
        }
    };

    const int row0 = wn + lr, row1 = wn + 16 + lr;
    const int m0 = ((row0 >> 2) & 7) << 1;
    const int m1 = ((row1 >> 2) & 7) << 1;
    const f32x4 z4 = {0.f, 0.f, 0.f, 0.f};

    // prologue
    load_stage(0);
    write_stage(Bs0);
    __syncthreads();
    if (STEPS > 1) load_stage(1);

    for (int s = 0; s < STEPS; s++) {
        const ushort* rbuf = (s & 1) ? Bs1 : Bs0;
        ushort*       wbuf = (s & 1) ? Bs0 : Bs1;

        f32x4 acc[2][2];  // [ni][mi], D[n][m]
        acc[0][0] = z4; acc[0][1] = z4; acc[1][0] = z4; acc[1][1] = z4;
        #pragma unroll
        for (int ks = 0; ks < 6; ks++) {
            const int g = 2 * lk + 8 * ks;   // even -> 16B-contiguous post-XOR
            short8v b0 = *(const short8v*)&rbuf[row0 * 196 + ((g ^ m0) << 2)];
            short8v b1 = *(const short8v*)&rbuf[row1 * 196 + ((g ^ m1) << 2)];
            acc[0][0] = __builtin_amdgcn_mfma_f32_16x16x32_bf16(b0, a[0][ks], acc[0][0], 0, 0, 0);
            acc[0][1] = __builtin_amdgcn_mfma_f32_16x16x32_bf16(b0, a[1][ks], acc[0][1], 0, 0, 0);
            acc[1][0] = __builtin_amdgcn_mfma_f32_16x16x32_bf16(b1, a[0][ks], acc[1][0], 0, 0, 0);
            acc[1][1] = __builtin_amdgcn_mfma_f32_16x16x32_bf16(b1, a[1][ks], acc[1][1], 0, 0, 0);
        }

        // D[n][m]: lane holds col m = lr, rows n = lk*4 + r (per 16-frag)
        long n0 = nbase + s * 64;
        #pragma unroll
        for (int ni = 0; ni < 2; ni++) {
            #pragma unroll
            for (int mi = 0; mi < 2; mi++) {
                long m  = (long)(mt * 64 + wm + mi * 16 + lr);
                long nn = n0 + wn + ni * 16 + lk * 4;
                if constexpr (OUT_F32) {
                    float* O = (float*)Op + (long)b * oStride + m * HW + nn;
                    float4 v4 = make_float4(acc[ni][mi][0], acc[ni][mi][1],
                                            acc[ni][mi][2], acc[ni][mi][3]);
                    *(float4*)O = v4;
                } else {
                    ushort* O = (ushort*)Op + (long)b * oStride + m * HW + nn;
                    *(uint2*)O = make_uint2(pkbf(acc[ni][mi][0], acc[ni][mi][1]),
                                            pkbf(acc[ni][mi][2], acc[ni][mi][3]));
                }
            }
        }

        if (s + 1 < STEPS) {
            write_stage(wbuf);        // consumes load(s+1); covers store-acks
            __syncthreads();          // ~nothing outstanding -> cheap drain
            if (s + 2 < STEPS) load_stage(s + 2);   // issue AFTER barrier
        }
    }
}

// ---------------- depthwise 3x3 (pad 1) + sumsq for q/k rows --------------
// one block per (b, channel) 128x128 plane; rolling 3-row window, 8-wide strips
__global__ __launch_bounds__(256) void k_dwconv(
    const ushort* __restrict__ qkv, const float* __restrict__ w_dw,
    ushort* __restrict__ qkv_dw, float* __restrict__ sumsq)
{
    __shared__ ushort tile[130 * 144];
    __shared__ float red[4];
    const int t = threadIdx.x;
    const int c = blockIdx.x, b = blockIdx.y;

    if (t < 144) { tile[t] = 0; tile[129 * 144 + t] = 0; }
    if (t < 128) { tile[(t + 1) * 144 + 7] = 0; tile[(t + 1) * 144 + 136] = 0; }

    const ushort* src = qkv + ((long)b * NC3 + c) * HW;
    #pragma unroll
    for (int i = 0; i < 8; i++) {
        int idx = t + 256 * i;
        int row = idx >> 4;
        int col8 = idx & 15;
        *(short8v*)(tile + (row + 1) * 144 + 8 + col8 * 8) =
            *(const short8v*)(src + (long)idx * 8);
    }
    __syncthreads();

    float wv[9];
    #pragma unroll
    for (int j = 0; j < 9; j++) wv[j] = w_dw[c * 9 + j];

    const int cb = (t & 15) * 8;
    const int r0 = (t >> 4) * 8;
    float win[3][16];

    auto load_row = [&](int tr, int slot) {
        #pragma unroll
        for (int j = 0; j < 4; j++) {
            ushort4 v = *(const ushort4*)(tile + tr * 144 + 4 + cb + j * 4);
            win[slot][j * 4 + 0] = bf2f(v.x);
            win[slot][j * 4 + 1] = bf2f(v.y);
            win[slot][j * 4 + 2] = bf2f(v.z);
            win[slot][j * 4 + 3] = bf2f(v.w);
        }
    };

    load_row(r0, 0);
    load_row(r0 + 1, 1);
    float ssq = 0.f;
    ushort* dst = qkv_dw + ((long)b * NC3 + c) * HW + (long)r0 * 128 + cb;

    #pragma unroll
    for (int rr = 0; rr < 8; rr++) {
        load_row(r0 + rr + 2, (rr + 2) % 3);
        const int s0 = rr % 3, s1 = (rr + 1) % 3, s2 = (rr + 2) % 3;
        float av[8];
        #pragma unroll
        for (int oc = 0; oc < 8; oc++) {
            float a = win[s0][oc + 3] * wv[0] + win[s0][oc + 4] * wv[1] + win[s0][oc + 5] * wv[2]
                    + win[s1][oc + 3] * wv[3] + win[s1][oc + 4] * wv[4] + win[s1][oc + 5] * wv[5]
                    + win[s2][oc + 3] * wv[6] + win[s2][oc + 4] * wv[7] + win[s2][oc + 5] * wv[8];
            ssq += a * a;
            av[oc] = a;
        }
        uint4 o4;
        o4.x = pkbf(av[0], av[1]); o4.y = pkbf(av[2], av[3]);
        o4.z = pkbf(av[4], av[5]); o4.w = pkbf(av[6], av[7]);
        *(uint4*)(dst + rr * 128) = o4;
    }

    #pragma unroll
    for (int off = 32; off > 0; off >>= 1) ssq += __shfl_down(ssq, off, 64);
    if ((t & 63) == 0) red[t >> 6] = ssq;
    __syncthreads();
    if (t == 0 && c < 2 * NC) sumsq[b * (2 * NC) + c] = red[0] + red[1] + red[2] + red[3];
}

// ---------------- attention scores: partial S = q . k^T -------------------
__global__ __launch_bounds__(256) void k_scores(
    const ushort* __restrict__ qkv_dw, float* __restrict__ Spart)
{
    const int bh = blockIdx.x, ks = blockIdx.y;
    const int b = bh >> 2, h = bh & 3;
    const int t = threadIdx.x, wid = t >> 6, lane = t & 63;
    const int lr = lane & 15, lk = lane >> 4;
    const ushort* qb = qkv_dw + ((long)b * NC3 + h * CPH) * HW;
    const ushort* kb = qb + (long)NC * HW;

    const f32x4 z4 = {0.f, 0.f, 0.f, 0.f};
    f32x4 acc[3][3];
    #pragma unroll
    for (int i = 0; i < 3; i++) {
        #pragma unroll
        for (int j = 0; j < 3; j++) acc[i][j] = z4;
    }

    const int kstart = ks * 2048 + wid * 512;
    for (int k0 = kstart; k0 < kstart + 512; k0 += 32) {
        short8v a[3], bv[3];
        #pragma unroll
        for (int i = 0; i < 3; i++) {
            a[i]  = *(const short8v*)(qb + (long)(i * 16 + lr) * HW + k0 + lk * 8);
            bv[i] = *(const short8v*)(kb + (long)(i * 16 + lr) * HW + k0 + lk * 8);
        }
        #pragma unroll
        for (int mi = 0; mi < 3; mi++) {
            #pragma unroll
            for (int ni = 0; ni < 3; ni++)
                acc[mi][ni] = __builtin_amdgcn_mfma_f32_16x16x32_bf16(a[mi], bv[ni], acc[mi][ni], 0, 0, 0);
        }
    }

    __shared__ float Sb[4 * 48 * 48];
    #pragma unroll
    for (int mi = 0; mi < 3; mi++) {
        #pragma unroll
        for (int ni = 0; ni < 3; ni++) {
            #pragma unroll
            for (int r = 0; r < 4; r++)
                Sb[wid * 2304 + (mi * 16 + lk * 4 + r) * 48 + ni * 16 + lr] = acc[mi][ni][r];
        }
    }
    __syncthreads();
    float* outp = Spart + ((long)ks * 32 + bh) * 2304;
    for (int i = t; i < 2304; i += 256)
        outp[i] = Sb[i] + Sb[2304 + i] + Sb[4608 + i] + Sb[6912 + i];
}

// ------- finalize: reduce partials, normalize, softmax, fold w_out --------
__global__ __launch_bounds__(256) void k_final(
    const float* __restrict__ Spart, const float* __restrict__ sumsq,
    const float* __restrict__ temperature, const float* __restrict__ wout,
    ushort* __restrict__ Mmat)
{
    const int bh = blockIdx.x, b = bh >> 2, h = bh & 3;
    const int t = threadIdx.x;
    __shared__ float S[48 * 48];
    __shared__ float P[48 * 48];
    __shared__ float invq[48], invk[48];
    if (t < 48) {
        invq[t] = 1.f / fmaxf(sqrtf(sumsq[b * (2 * NC) + h * CPH + t]), 1e-12f);
        invk[t] = 1.f / fmaxf(sqrtf(sumsq[b * (2 * NC) + NC + h * CPH + t]), 1e-12f);
    }
    __syncthreads();
    const float T = temperature[h];
    for (int i = t; i < 2304; i += 256) {
        float s = 0.f;
        #pragma unroll
        for (int p = 0; p < 8; p++) s += Spart[((long)p * 32 + bh) * 2304 + i];
        int cc = i / 48, dd = i - cc * 48;
        S[i] = s * invq[cc] * invk[dd] * T;
    }
    __syncthreads();
    if (t < 48) {
        float m = -1e30f;
        for (int d = 0; d < 48; d++) m = fmaxf(m, S[t * 48 + d]);
        float sum = 0.f;
        for (int d = 0; d < 48; d++) { float e = __expf(S[t * 48 + d] - m); P[t * 48 + d] = e; sum += e; }
        float inv = 1.f / sum;
        for (int d = 0; d < 48; d++) P[t * 48 + d] *= inv;
    }
    __syncthreads();
    for (int i = t; i < NC * CPH; i += 256) {
        int o = i / 48, d = i - (i / 48) * 48;
        float a = 0.f;
        for (int c2 = 0; c2 < 48; c2++)
            a += wout[o * NC + h * CPH + c2] * P[c2 * 48 + d];
        Mmat[(long)b * NC * NC + (long)o * NC + h * CPH + d] = f2bf(a);
    }
}

// --------------------------------------------------------------------------
extern "C" void kernel_launch(void* const* d_in, const int* in_sizes, int n_in,
                              void* d_out, int out_size, void* d_ws, size_t ws_size,
                              hipStream_t stream)
{
    (void)in_sizes; (void)n_in; (void)out_size;
    const float* x     = (const float*)d_in[0];
    const float* w_in  = (const float*)d_in[1];
    const float* w_dw  = (const float*)d_in[2];
    const float* temp  = (const float*)d_in[3];
    const float* w_out = (const float*)d_in[4];
    float* outp = (float*)d_out;

    const long QKV_BYTES = (long)NB * NC3 * HW * 2;      // 150,994,944
    char* ws = (char*)d_ws;
    if (ws_size < 305172480UL) return;
    ushort* qkv    = (ushort*)(ws);
    ushort* qkv_dw = (ushort*)(ws + QKV_BYTES);
    ushort* w_bf   = (ushort*)(ws + 2 * QKV_BYTES);
    float*  sumsq  = (float*) (ws + 302211072L);
    float*  Spart  = (float*) (ws + 302223360L);
    ushort* Mmat   = (ushort*)(ws + 304582656L);

    k_prep<<<dim3(432), 256, 0, stream>>>(w_in, w_bf);

    // conv_in: qkv[b][o][n] = sum_c w_in[o][c] x[b][c][n]; A = w_bf (aStride 0)
    // ncnk in grid.x: the 9 mt-blocks sharing an x-chunk differ by 32 in
    // linear id (32 % 8 == 0 -> same XCD -> chunk fetched from HBM once)
    k_gemm8<true, false, 8><<<dim3(32, 9, NB), 256, 0, stream>>>(
        w_bf, 0L, x, (long)NC * HW, qkv, (long)NC3 * HW);

    k_dwconv<<<dim3(NC3, NB), 256, 0, stream>>>(qkv, w_dw, qkv_dw, sumsq);

    k_scores<<<dim3(32, 8), 256, 0, stream>>>(qkv_dw, Spart);

    k_final<<<dim3(32), 256, 0, stream>>>(Spart, sumsq, temp, w_out, Mmat);

    // out[b] = M[b] (192x192) @ v[b] (192 x HW)
    k_gemm8<false, true, 4><<<dim3(64, 3, NB), 256, 0, stream>>>(
        Mmat, (long)NC * NC, qkv_dw + (long)(2 * NC) * HW, (long)NC3 * HW,
        outp, (long)NC * HW);
}

// Round 14
// 245.855 us; speedup vs baseline: 1.2676x; 1.2676x over previous
//
#include <hip/hip_runtime.h>
#include <hip/hip_bf16.h>

#define HW 16384
#define NB 8
#define NC 192
#define NC3 576
#define NHEADS 4
#define CPH 48

typedef __attribute__((ext_vector_type(8))) short short8v;
typedef __attribute__((ext_vector_type(4))) float f32x4;

__device__ __forceinline__ float bf2f(ushort u) {
    union { unsigned int u; float f; } w; w.u = ((unsigned int)u) << 16; return w.f;
}
__device__ __forceinline__ ushort f2bf(float f) {
    union { float f; unsigned int u; } w; w.f = f;
    return (ushort)((w.u + 0x7FFFu + ((w.u >> 16) & 1u)) >> 16);
}
// packed f32x2 -> bf16x2 (RNE), single VALU inst; lo -> [15:0], hi -> [31:16]
__device__ __forceinline__ unsigned int pkbf(float lo, float hi) {
    unsigned int r;
    asm("v_cvt_pk_bf16_f32 %0, %1, %2" : "=v"(r) : "v"(lo), "v"(hi));
    return r;
}

// ---------------- prep: convert w_in (576x192 f32) to bf16 ----------------
__global__ __launch_bounds__(256) void k_prep(const float* __restrict__ w_in,
                                              ushort* __restrict__ w_bf) {
    int i = blockIdx.x * 256 + threadIdx.x;
    if (i < NC3 * NC) w_bf[i] = f2bf(w_in[i]);
}

// ------- GEMM v9: r12 pipeline + MTILES m-tiles per block (A in regs) -----
// Out[b][m][n] = sum_k A[b][m][k] * B[b][k][n],  K = 192.
// Each block owns MTILES consecutive 64-row m-tiles (A fragments resident in
// 48*MTILES VGPRs, loaded once) and STEPS consecutive 64-col n-tiles.
// Per step (r12's proven schedule): write staged regs -> swizzled LDS ;
// issue next step's global loads ; barrier ; for each mt: MFMA + stores ;
// barrier.  m-split reduced 9->3 cuts redundant x re-reads through L2 by 3x
// (the identified ~105us L2-path floor at split=9).
// LDS addressing (8B granules g = k>>2):
//   addr_ushort(n,k) = n*196 + ((g ^ (((n>>2)&7)<<1)) << 2) + (k&3)
// Staging mapping (256B global segments): nl=(t&15)*4, kq=t>>4.
template<bool B_F32, bool OUT_F32, int STEPS, int MTILES>
__global__ __launch_bounds__(256) void k_gemm9(
    const ushort* __restrict__ Abase, long aStride,
    const void* __restrict__ Bp, long bStride,
    void* __restrict__ Op, long oStride)
{
    __shared__ ushort Bs[64 * 196];
    const int t = threadIdx.x;
    const int ncnk = blockIdx.x, mtg = blockIdx.y, b = blockIdx.z;
    const int wid = t >> 6, lane = t & 63;
    const int wm = (wid >> 1) * 32, wn = (wid & 1) * 32;
    const int lr = lane & 15, lk = lane >> 4;
    const int mbase = mtg * (MTILES * 64);

    // ---- A fragments in registers for all MTILES tiles (rows k-contiguous)
    short8v a[MTILES][2][6];
    #pragma unroll
    for (int mt = 0; mt < MTILES; mt++) {
        const ushort* A = Abase + (long)b * aStride
                        + (long)(mbase + mt * 64 + wm + lr) * NC + lk * 8;
        #pragma unroll
        for (int mi = 0; mi < 2; mi++) {
            #pragma unroll
            for (int ks = 0; ks < 6; ks++)
                a[mt][mi][ks] = *(const short8v*)(A + mi * 16 * NC + ks * 32);
        }
    }

    const int nl = (t & 15) * 4;     // 4 consecutive n this thread stages
    const int kq = t >> 4;           // k-group: k = kq*12 .. kq*12+11
    const int k0 = kq * 12;
    const int wmsk = (t & 7) << 1;   // = ((n>>2)&7)<<1 for n = nl+i (i<4)
    const long nbase = (long)ncnk * (STEPS * 64);

    float4 fr[12];
    ushort4 ur[12];

    auto load_stage = [&](int s) {
        long n0 = nbase + s * 64;
        if constexpr (B_F32) {
            const float* B = (const float*)Bp + (long)b * bStride
                           + (long)k0 * HW + n0 + nl;
            #pragma unroll
            for (int kk = 0; kk < 12; kk++)
                fr[kk] = *(const float4*)(B + (long)kk * HW);
        } else {
            const ushort* B = (const ushort*)Bp + (long)b * bStride
                            + (long)k0 * HW + n0 + nl;
            #pragma unroll
            for (int kk = 0; kk < 12; kk++)
                ur[kk] = *(const ushort4*)(B + (long)kk * HW);
        }
    };

    auto write_stage = [&]() {
        #pragma unroll
        for (int i = 0; i < 4; i++) {     // n = nl + i (compile-time i)
            const int n = nl + i;
            unsigned int u[6];            // k0..k0+11 packed as bf16x2
            if constexpr (B_F32) {
                #pragma unroll
                for (int p = 0; p < 6; p++)
                    u[p] = pkbf(((const float*)&fr[2 * p])[i],
                                ((const float*)&fr[2 * p + 1])[i]);
            } else {
                #pragma unroll
                for (int p = 0; p < 6; p++) {
                    unsigned int lo = ((const ushort*)&ur[2 * p])[i];
                    unsigned int hi = ((const ushort*)&ur[2 * p + 1])[i];
                    u[p] = lo | (hi << 16);
                }
            }
            #pragma unroll
            for (int seg = 0; seg < 3; seg++) {
                const int g = 3 * kq + seg;          // unswizzled 8B granule
                *(uint2*)&Bs[n * 196 + ((g ^ wmsk) << 2)] =
                    make_uint2(u[2 * seg], u[2 * seg + 1]);
            }
        }
    };

    const int row0 = wn + lr, row1 = wn + 16 + lr;
    const int m0 = ((row0 >> 2) & 7) << 1;
    const int m1 = ((row1 >> 2) & 7) << 1;
    const f32x4 z4 = {0.f, 0.f, 0.f, 0.f};

    load_stage(0);
    for (int s = 0; s < STEPS; s++) {
        write_stage();
        if (s + 1 < STEPS) load_stage(s + 1);
        __syncthreads();

        long n0 = nbase + s * 64;
        #pragma unroll
        for (int mt = 0; mt < MTILES; mt++) {
            f32x4 acc[2][2];  // [ni][mi], D[n][m]
            acc[0][0] = z4; acc[0][1] = z4; acc[1][0] = z4; acc[1][1] = z4;
            #pragma unroll
            for (int ks = 0; ks < 6; ks++) {
                const int g = 2 * lk + 8 * ks;  // even -> 16B-contiguous post-XOR
                short8v b0 = *(const short8v*)&Bs[row0 * 196 + ((g ^ m0) << 2)];
                short8v b1 = *(const short8v*)&Bs[row1 * 196 + ((g ^ m1) << 2)];
                acc[0][0] = __builtin_amdgcn_mfma_f32_16x16x32_bf16(b0, a[mt][0][ks], acc[0][0], 0, 0, 0);
                acc[0][1] = __builtin_amdgcn_mfma_f32_16x16x32_bf16(b0, a[mt][1][ks], acc[0][1], 0, 0, 0);
                acc[1][0] = __builtin_amdgcn_mfma_f32_16x16x32_bf16(b1, a[mt][0][ks], acc[1][0], 0, 0, 0);
                acc[1][1] = __builtin_amdgcn_mfma_f32_16x16x32_bf16(b1, a[mt][1][ks], acc[1][1], 0, 0, 0);
            }

            // D[n][m]: lane holds col m = lr, rows n = lk*4 + r (per 16-frag)
            #pragma unroll
            for (int ni = 0; ni < 2; ni++) {
                #pragma unroll
                for (int mi = 0; mi < 2; mi++) {
                    long m  = (long)(mbase + mt * 64 + wm + mi * 16 + lr);
                    long nn = n0 + wn + ni * 16 + lk * 4;
                    if constexpr (OUT_F32) {
                        float* O = (float*)Op + (long)b * oStride + m * HW + nn;
                        float4 v4 = make_float4(acc[ni][mi][0], acc[ni][mi][1],
                                                acc[ni][mi][2], acc[ni][mi][3]);
                        *(float4*)O = v4;
                    } else {
                        ushort* O = (ushort*)Op + (long)b * oStride + m * HW + nn;
                        *(uint2*)O = make_uint2(pkbf(acc[ni][mi][0], acc[ni][mi][1]),
                                                pkbf(acc[ni][mi][2], acc[ni][mi][3]));
                    }
                }
            }
        }
        __syncthreads();
    }
}

// ---------------- depthwise 3x3 (pad 1) + sumsq for q/k rows --------------
// one block per (b, channel) 128x128 plane; rolling 3-row window, 8-wide strips
__global__ __launch_bounds__(256) void k_dwconv(
    const ushort* __restrict__ qkv, const float* __restrict__ w_dw,
    ushort* __restrict__ qkv_dw, float* __restrict__ sumsq)
{
    __shared__ ushort tile[130 * 144];
    __shared__ float red[4];
    const int t = threadIdx.x;
    const int c = blockIdx.x, b = blockIdx.y;

    if (t < 144) { tile[t] = 0; tile[129 * 144 + t] = 0; }
    if (t < 128) { tile[(t + 1) * 144 + 7] = 0; tile[(t + 1) * 144 + 136] = 0; }

    const ushort* src = qkv + ((long)b * NC3 + c) * HW;
    #pragma unroll
    for (int i = 0; i < 8; i++) {
        int idx = t + 256 * i;
        int row = idx >> 4;
        int col8 = idx & 15;
        *(short8v*)(tile + (row + 1) * 144 + 8 + col8 * 8) =
            *(const short8v*)(src + (long)idx * 8);
    }
    __syncthreads();

    float wv[9];
    #pragma unroll
    for (int j = 0; j < 9; j++) wv[j] = w_dw[c * 9 + j];

    const int cb = (t & 15) * 8;
    const int r0 = (t >> 4) * 8;
    float win[3][16];

    auto load_row = [&](int tr, int slot) {
        #pragma unroll
        for (int j = 0; j < 4; j++) {
            ushort4 v = *(const ushort4*)(tile + tr * 144 + 4 + cb + j * 4);
            win[slot][j * 4 + 0] = bf2f(v.x);
            win[slot][j * 4 + 1] = bf2f(v.y);
            win[slot][j * 4 + 2] = bf2f(v.z);
            win[slot][j * 4 + 3] = bf2f(v.w);
        }
    };

    load_row(r0, 0);
    load_row(r0 + 1, 1);
    float ssq = 0.f;
    ushort* dst = qkv_dw + ((long)b * NC3 + c) * HW + (long)r0 * 128 + cb;

    #pragma unroll
    for (int rr = 0; rr < 8; rr++) {
        load_row(r0 + rr + 2, (rr + 2) % 3);
        const int s0 = rr % 3, s1 = (rr + 1) % 3, s2 = (rr + 2) % 3;
        float av[8];
        #pragma unroll
        for (int oc = 0; oc < 8; oc++) {
            float a = win[s0][oc + 3] * wv[0] + win[s0][oc + 4] * wv[1] + win[s0][oc + 5] * wv[2]
                    + win[s1][oc + 3] * wv[3] + win[s1][oc + 4] * wv[4] + win[s1][oc + 5] * wv[5]
                    + win[s2][oc + 3] * wv[6] + win[s2][oc + 4] * wv[7] + win[s2][oc + 5] * wv[8];
            ssq += a * a;
            av[oc] = a;
        }
        uint4 o4;
        o4.x = pkbf(av[0], av[1]); o4.y = pkbf(av[2], av[3]);
        o4.z = pkbf(av[4], av[5]); o4.w = pkbf(av[6], av[7]);
        *(uint4*)(dst + rr * 128) = o4;
    }

    #pragma unroll
    for (int off = 32; off > 0; off >>= 1) ssq += __shfl_down(ssq, off, 64);
    if ((t & 63) == 0) red[t >> 6] = ssq;
    __syncthreads();
    if (t == 0 && c < 2 * NC) sumsq[b * (2 * NC) + c] = red[0] + red[1] + red[2] + red[3];
}

// ---------------- attention scores: partial S = q . k^T -------------------
__global__ __launch_bounds__(256) void k_scores(
    const ushort* __restrict__ qkv_dw, float* __restrict__ Spart)
{
    const int bh = blockIdx.x, ks = blockIdx.y;
    const int b = bh >> 2, h = bh & 3;
    const int t = threadIdx.x, wid = t >> 6, lane = t & 63;
    const int lr = lane & 15, lk = lane >> 4;
    const ushort* qb = qkv_dw + ((long)b * NC3 + h * CPH) * HW;
    const ushort* kb = qb + (long)NC * HW;

    const f32x4 z4 = {0.f, 0.f, 0.f, 0.f};
    f32x4 acc[3][3];
    #pragma unroll
    for (int i = 0; i < 3; i++) {
        #pragma unroll
        for (int j = 0; j < 3; j++) acc[i][j] = z4;
    }

    const int kstart = ks * 2048 + wid * 512;
    for (int k0 = kstart; k0 < kstart + 512; k0 += 32) {
        short8v a[3], bv[3];
        #pragma unroll
        for (int i = 0; i < 3; i++) {
            a[i]  = *(const short8v*)(qb + (long)(i * 16 + lr) * HW + k0 + lk * 8);
            bv[i] = *(const short8v*)(kb + (long)(i * 16 + lr) * HW + k0 + lk * 8);
        }
        #pragma unroll
        for (int mi = 0; mi < 3; mi++) {
            #pragma unroll
            for (int ni = 0; ni < 3; ni++)
                acc[mi][ni] = __builtin_amdgcn_mfma_f32_16x16x32_bf16(a[mi], bv[ni], acc[mi][ni], 0, 0, 0);
        }
    }

    __shared__ float Sb[4 * 48 * 48];
    #pragma unroll
    for (int mi = 0; mi < 3; mi++) {
        #pragma unroll
        for (int ni = 0; ni < 3; ni++) {
            #pragma unroll
            for (int r = 0; r < 4; r++)
                Sb[wid * 2304 + (mi * 16 + lk * 4 + r) * 48 + ni * 16 + lr] = acc[mi][ni][r];
        }
    }
    __syncthreads();
    float* outp = Spart + ((long)ks * 32 + bh) * 2304;
    for (int i = t; i < 2304; i += 256)
        outp[i] = Sb[i] + Sb[2304 + i] + Sb[4608 + i] + Sb[6912 + i];
}

// ------- finalize: reduce partials, normalize, softmax, fold w_out --------
__global__ __launch_bounds__(256) void k_final(
    const float* __restrict__ Spart, const float* __restrict__ sumsq,
    const float* __restrict__ temperature, const float* __restrict__ wout,
    ushort* __restrict__ Mmat)
{
    const int bh = blockIdx.x, b = bh >> 2, h = bh & 3;
    const int t = threadIdx.x;
    __shared__ float S[48 * 48];
    __shared__ float P[48 * 48];
    __shared__ float invq[48], invk[48];
    if (t < 48) {
        invq[t] = 1.f / fmaxf(sqrtf(sumsq[b * (2 * NC) + h * CPH + t]), 1e-12f);
        invk[t] = 1.f / fmaxf(sqrtf(sumsq[b * (2 * NC) + NC + h * CPH + t]), 1e-12f);
    }
    __syncthreads();
    const float T = temperature[h];
    for (int i = t; i < 2304; i += 256) {
        float s = 0.f;
        #pragma unroll
        for (int p = 0; p < 8; p++) s += Spart[((long)p * 32 + bh) * 2304 + i];
        int cc = i / 48, dd = i - cc * 48;
        S[i] = s * invq[cc] * invk[dd] * T;
    }
    __syncthreads();
    if (t < 48) {
        float m = -1e30f;
        for (int d = 0; d < 48; d++) m = fmaxf(m, S[t * 48 + d]);
        float sum = 0.f;
        for (int d = 0; d < 48; d++) { float e = __expf(S[t * 48 + d] - m); P[t * 48 + d] = e; sum += e; }
        float inv = 1.f / sum;
        for (int d = 0; d < 48; d++) P[t * 48 + d] *= inv;
    }
    __syncthreads();
    for (int i = t; i < NC * CPH; i += 256) {
        int o = i / 48, d = i - (i / 48) * 48;
        float a = 0.f;
        for (int c2 = 0; c2 < 48; c2++)
            a += wout[o * NC + h * CPH + c2] * P[c2 * 48 + d];
        Mmat[(long)b * NC * NC + (long)o * NC + h * CPH + d] = f2bf(a);
    }
}

// --------------------------------------------------------------------------
extern "C" void kernel_launch(void* const* d_in, const int* in_sizes, int n_in,
                              void* d_out, int out_size, void* d_ws, size_t ws_size,
                              hipStream_t stream)
{
    (void)in_sizes; (void)n_in; (void)out_size;
    const float* x     = (const float*)d_in[0];
    const float* w_in  = (const float*)d_in[1];
    const float* w_dw  = (const float*)d_in[2];
    const float* temp  = (const float*)d_in[3];
    const float* w_out = (const float*)d_in[4];
    float* outp = (float*)d_out;

    const long QKV_BYTES = (long)NB * NC3 * HW * 2;      // 150,994,944
    char* ws = (char*)d_ws;
    if (ws_size < 305172480UL) return;
    ushort* qkv    = (ushort*)(ws);
    ushort* qkv_dw = (ushort*)(ws + QKV_BYTES);
    ushort* w_bf   = (ushort*)(ws + 2 * QKV_BYTES);
    float*  sumsq  = (float*) (ws + 302211072L);
    float*  Spart  = (float*) (ws + 302223360L);
    ushort* Mmat   = (ushort*)(ws + 304582656L);

    k_prep<<<dim3(432), 256, 0, stream>>>(w_in, w_bf);

    // conv_in: qkv[b][o][n] = sum_c w_in[o][c] x[b][c][n]; A = w_bf (aStride 0)
    // m-split = 3 (was 9): 3 mtg-blocks re-read each x chunk (L2 traffic 3x
    // lower); they differ by 32 in linear id (mod 8 == 0 -> same XCD).
    k_gemm9<true, false, 8, 3><<<dim3(32, 3, NB), 256, 0, stream>>>(
        w_bf, 0L, x, (long)NC * HW, qkv, (long)NC3 * HW);

    k_dwconv<<<dim3(NC3, NB), 256, 0, stream>>>(qkv, w_dw, qkv_dw, sumsq);

    k_scores<<<dim3(32, 8), 256, 0, stream>>>(qkv_dw, Spart);

    k_final<<<dim3(32), 256, 0, stream>>>(Spart, sumsq, temp, w_out, Mmat);

    // out[b] = M[b] (192x192) @ v[b] (192 x HW); MTILES=3 covers all of M
    k_gemm9<false, true, 4, 3><<<dim3(64, 1, NB), 256, 0, stream>>>(
        Mmat, (long)NC * NC, qkv_dw + (long)(2 * NC) * HW, (long)NC3 * HW,
        outp, (long)NC * HW);
}